// Round 1
// baseline (4831.085 us; speedup 1.0000x reference)
//
#include <hip/hip_runtime.h>
#include <hip/hip_bf16.h>
#include <cmath>

constexpr int kCIN = 128, kHID = 256, kOUT = 349;
constexpr int kNT = 4, kET = 5;
constexpr int kN0 = 120000, kN1 = 40000, kN2 = 10000;

// ---------------- input gather: h0[i] = table[nt][min(li, rows-1)] ----------
__global__ void k_gather(const int* __restrict__ n_id, const float* __restrict__ x0,
                         const float* __restrict__ e1, const float* __restrict__ e2,
                         const float* __restrict__ e3, const int* __restrict__ ntype,
                         const int* __restrict__ lidx, float* __restrict__ h0,
                         int* __restrict__ nt0)
{
    int row = blockIdx.x * 8 + (threadIdx.x >> 5);
    if (row >= kN0) return;
    int lane = threadIdx.x & 31;
    int gid = n_id[row];
    int nt = ntype[gid];
    int li = lidx[gid];
    const float* tab;
    int rows;
    if (nt == 0)      { tab = x0; rows = 100000; }
    else if (nt == 1) { tab = e1; rows = 50000; }
    else if (nt == 2) { tab = e2; rows = 50000; }
    else              { tab = e3; rows = 50000; }
    int idx = li < rows ? li : rows - 1;
    float4 v = reinterpret_cast<const float4*>(tab + (size_t)idx * kCIN)[lane];
    reinterpret_cast<float4*>(h0 + (size_t)row * kCIN)[lane] = v;
    if (lane == 0) nt0[row] = nt;
}

// ---------------- edge scatter: sums[dst*5+et] += h[src]; cnts += 1 ---------
template<int C>
__global__ void k_scatter(const int* __restrict__ src, const int* __restrict__ dst,
                          const int* __restrict__ eid, const int* __restrict__ etype,
                          const float* __restrict__ h, float* __restrict__ sums,
                          float* __restrict__ cnts, int E)
{
    constexpr int L = C / 4;          // lanes per edge (float4 each)
    constexpr int EPB = 256 / L;      // edges per block
    int e = blockIdx.x * EPB + threadIdx.x / L;
    if (e >= E) return;
    int lane = threadIdx.x % L;
    int s = src[e];
    int d = dst[e];
    int et = etype[eid[e]];
    size_t seg = (size_t)d * kET + et;
    float4 v = reinterpret_cast<const float4*>(h + (size_t)s * C)[lane];
    float* p = sums + seg * C + lane * 4;
    unsafeAtomicAdd(p + 0, v.x);
    unsafeAtomicAdd(p + 1, v.y);
    unsafeAtomicAdd(p + 2, v.z);
    unsafeAtomicAdd(p + 3, v.w);
    if (lane == 0) unsafeAtomicAdd(cnts + seg, 1.0f);
}

__global__ void k_invc(const float* __restrict__ cnts, float* __restrict__ invc, int n)
{
    int i = blockIdx.x * 256 + threadIdx.x;
    if (i < n) invc[i] = 1.0f / fmaxf(cnts[i], 1.0f);
}

// ---------------- fused GEMM: out = [mean | onehot(nt)*h] @ [relW; rootW] + rootb[nt]
// virtual A: k < K1=5*C : sums[n*K1+k] * invc[n*5 + k/C]
//            k >= K1    : (nt[n] == (k-K1)/C) ? h[n*C + (k-K1)%C] : 0
template<int C, int RELU>
__global__ __launch_bounds__(256) void k_gemm(
    int M, int N,
    const float* __restrict__ sums, const float* __restrict__ invc,
    const float* __restrict__ h, const float* __restrict__ relW,
    const float* __restrict__ rootW, const float* __restrict__ rootb,
    const int* __restrict__ nt0, float* __restrict__ out)
{
    constexpr int K1 = kET * C;
    constexpr int K = K1 + kNT * C;
    __shared__ float aT[32][64];   // [kk][row]
    __shared__ float bT[32][64];   // [kk][col]
    const int row0 = blockIdx.x * 64;
    const int col0 = blockIdx.y * 64;
    const int tx = threadIdx.x & 15;
    const int ty = threadIdx.x >> 4;
    float acc[4][4] = {};
    const int ar = threadIdx.x >> 2;          // 0..63 row within tile
    const int akb = (threadIdx.x & 3) << 3;   // 0,8,16,24 k-offset
    const int an = row0 + ar;

    for (int k0 = 0; k0 < K; k0 += 32) {
        float av[8];
#pragma unroll
        for (int i = 0; i < 8; i++) av[i] = 0.f;
        if (an < M) {
            int kg = k0 + akb;
            if (kg < K1) {
                float sc = invc[an * kET + kg / C];
                const float4* p = reinterpret_cast<const float4*>(sums + (size_t)an * K1 + kg);
                float4 u0 = p[0], u1 = p[1];
                av[0] = u0.x * sc; av[1] = u0.y * sc; av[2] = u0.z * sc; av[3] = u0.w * sc;
                av[4] = u1.x * sc; av[5] = u1.y * sc; av[6] = u1.z * sc; av[7] = u1.w * sc;
            } else {
                int kr = kg - K1;
                if (nt0[an] == kr / C) {
                    const float4* p = reinterpret_cast<const float4*>(h + (size_t)an * C + (kr & (C - 1)));
                    float4 u0 = p[0], u1 = p[1];
                    av[0] = u0.x; av[1] = u0.y; av[2] = u0.z; av[3] = u0.w;
                    av[4] = u1.x; av[5] = u1.y; av[6] = u1.z; av[7] = u1.w;
                }
            }
        }
#pragma unroll
        for (int i = 0; i < 8; i++) aT[akb + i][ar] = av[i];

#pragma unroll
        for (int j = 0; j < 8; j++) {
            int e = j * 256 + threadIdx.x;
            int kk = e >> 6, o = e & 63;
            int kg = k0 + kk, col = col0 + o;
            float v = 0.f;
            if (col < N) {
                if (kg < K1) v = relW[(size_t)kg * N + col];
                else         v = rootW[(size_t)(kg - K1) * N + col];
            }
            bT[kk][o] = v;
        }
        __syncthreads();
#pragma unroll
        for (int kk = 0; kk < 32; kk++) {
            float4 a = *reinterpret_cast<const float4*>(&aT[kk][ty * 4]);
            float4 b = *reinterpret_cast<const float4*>(&bT[kk][tx * 4]);
            acc[0][0] += a.x * b.x; acc[0][1] += a.x * b.y; acc[0][2] += a.x * b.z; acc[0][3] += a.x * b.w;
            acc[1][0] += a.y * b.x; acc[1][1] += a.y * b.y; acc[1][2] += a.y * b.z; acc[1][3] += a.y * b.w;
            acc[2][0] += a.z * b.x; acc[2][1] += a.z * b.y; acc[2][2] += a.z * b.z; acc[2][3] += a.z * b.w;
            acc[3][0] += a.w * b.x; acc[3][1] += a.w * b.y; acc[3][2] += a.w * b.z; acc[3][3] += a.w * b.w;
        }
        __syncthreads();
    }
#pragma unroll
    for (int i = 0; i < 4; i++) {
        int n = row0 + ty * 4 + i;
        if (n >= M) continue;
        int t = nt0[n];
#pragma unroll
        for (int j = 0; j < 4; j++) {
            int col = col0 + tx * 4 + j;
            if (col >= N) continue;
            float v = acc[i][j] + rootb[t * N + col];
            if (RELU) v = fmaxf(v, 0.f);
            out[(size_t)n * N + col] = v;
        }
    }
}

// ---------------- in-place log_softmax over rows of N cols ------------------
__global__ void k_logsm(float* __restrict__ out, int M, int N)
{
    int row = blockIdx.x * 4 + (threadIdx.x >> 6);
    if (row >= M) return;
    int lane = threadIdx.x & 63;
    float* p = out + (size_t)row * N;
    float mx = -3.4e38f;
    for (int c = lane; c < N; c += 64) mx = fmaxf(mx, p[c]);
#pragma unroll
    for (int o = 32; o > 0; o >>= 1) mx = fmaxf(mx, __shfl_xor(mx, o));
    float s = 0.f;
    for (int c = lane; c < N; c += 64) s += expf(p[c] - mx);
#pragma unroll
    for (int o = 32; o > 0; o >>= 1) s += __shfl_xor(s, o);
    float lse = mx + logf(s);
    for (int c = lane; c < N; c += 64) p[c] -= lse;
}

extern "C" void kernel_launch(void* const* d_in, const int* in_sizes, int n_in,
                              void* d_out, int out_size, void* d_ws, size_t ws_size,
                              hipStream_t stream)
{
    const int*   n_id   = (const int*)d_in[0];
    const float* x0     = (const float*)d_in[1];
    const int*   src0   = (const int*)d_in[2];
    const int*   dst0   = (const int*)d_in[3];
    const int*   eid0   = (const int*)d_in[4];
    const int*   src1   = (const int*)d_in[5];
    const int*   dst1   = (const int*)d_in[6];
    const int*   eid1   = (const int*)d_in[7];
    const int*   etype  = (const int*)d_in[8];
    const int*   ntype  = (const int*)d_in[9];
    const int*   lidx   = (const int*)d_in[10];
    const float* emb1   = (const float*)d_in[11];
    const float* emb2   = (const float*)d_in[12];
    const float* emb3   = (const float*)d_in[13];
    const float* relW0  = (const float*)d_in[14];
    const float* rootW0 = (const float*)d_in[15];
    const float* rootb0 = (const float*)d_in[16];
    const float* relW1  = (const float*)d_in[17];
    const float* rootW1 = (const float*)d_in[18];
    const float* rootb1 = (const float*)d_in[19];
    float* out = (float*)d_out;

    const int E0 = in_sizes[2];
    const int E1 = in_sizes[5];

    char* ws = (char*)d_ws;
    size_t off = 0;
    auto alloc = [&](size_t bytes) -> void* {
        void* p = ws + off;
        off = (off + bytes + 255) & ~(size_t)255;
        return p;
    };
    float* h0    = (float*)alloc((size_t)kN0 * kCIN * 4);
    int*   nt0   = (int*)alloc((size_t)kN0 * 4);
    float* sums0 = (float*)alloc((size_t)kN1 * kET * kCIN * 4);
    float* cnts0 = (float*)alloc((size_t)kN1 * kET * 4);
    float* invc0 = (float*)alloc((size_t)kN1 * kET * 4);
    float* h1    = (float*)alloc((size_t)kN1 * kHID * 4);
    float* sums1 = (float*)alloc((size_t)kN2 * kET * kHID * 4);
    float* cnts1 = (float*)alloc((size_t)kN2 * kET * 4);
    float* invc1 = (float*)alloc((size_t)kN2 * kET * 4);

    hipMemsetAsync(sums0, 0, (size_t)kN1 * kET * kCIN * 4, stream);
    hipMemsetAsync(cnts0, 0, (size_t)kN1 * kET * 4, stream);
    hipMemsetAsync(sums1, 0, (size_t)kN2 * kET * kHID * 4, stream);
    hipMemsetAsync(cnts1, 0, (size_t)kN2 * kET * 4, stream);

    k_gather<<<(kN0 + 7) / 8, 256, 0, stream>>>(n_id, x0, emb1, emb2, emb3, ntype, lidx, h0, nt0);

    k_scatter<kCIN><<<(E0 + 7) / 8, 256, 0, stream>>>(src0, dst0, eid0, etype, h0, sums0, cnts0, E0);
    k_invc<<<(kN1 * kET + 255) / 256, 256, 0, stream>>>(cnts0, invc0, kN1 * kET);
    dim3 g0(kN1 / 64, kHID / 64);
    k_gemm<kCIN, 1><<<g0, 256, 0, stream>>>(kN1, kHID, sums0, invc0, h0, relW0, rootW0, rootb0, nt0, h1);

    k_scatter<kHID><<<(E1 + 3) / 4, 256, 0, stream>>>(src1, dst1, eid1, etype, h1, sums1, cnts1, E1);
    k_invc<<<(kN2 * kET + 255) / 256, 256, 0, stream>>>(cnts1, invc1, kN2 * kET);
    dim3 g1((kN2 + 63) / 64, (kOUT + 63) / 64);
    k_gemm<kHID, 0><<<g1, 256, 0, stream>>>(kN2, kOUT, sums1, invc1, h1, relW1, rootW1, rootb1, nt0, out);

    k_logsm<<<(kN2 + 3) / 4, 256, 0, stream>>>(out, kN2, kOUT);
}

// Round 2
// 1154.556 us; speedup vs baseline: 4.1844x; 4.1844x over previous
//
#include <hip/hip_runtime.h>
#include <hip/hip_bf16.h>
#include <cmath>

constexpr int kCIN = 128, kHID = 256, kOUT = 349;
constexpr int kNT = 4, kET = 5;
constexpr int kN0 = 120000, kN1 = 40000, kN2 = 10000;
constexpr int kNSEG0 = kN1 * kET;   // 200000
constexpr int kNSEG1 = kN2 * kET;   // 50000

// ---------------- input gather: h0[i] = table[nt][min(li, rows-1)] ----------
__global__ void k_gather(const int* __restrict__ n_id, const float* __restrict__ x0,
                         const float* __restrict__ e1, const float* __restrict__ e2,
                         const float* __restrict__ e3, const int* __restrict__ ntype,
                         const int* __restrict__ lidx, float* __restrict__ h0,
                         int* __restrict__ nt0)
{
    int row = blockIdx.x * 8 + (threadIdx.x >> 5);
    if (row >= kN0) return;
    int lane = threadIdx.x & 31;
    int gid = n_id[row];
    int nt = ntype[gid];
    int li = lidx[gid];
    const float* tab;
    int rows;
    if (nt == 0)      { tab = x0; rows = 100000; }
    else if (nt == 1) { tab = e1; rows = 50000; }
    else if (nt == 2) { tab = e2; rows = 50000; }
    else              { tab = e3; rows = 50000; }
    int idx = li < rows ? li : rows - 1;
    float4 v = reinterpret_cast<const float4*>(tab + (size_t)idx * kCIN)[lane];
    reinterpret_cast<float4*>(h0 + (size_t)row * kCIN)[lane] = v;
    if (lane == 0) nt0[row] = nt;
}

// ---------------- CSR build: histogram, scan, reorder -----------------------
__global__ void k_hist(const int* __restrict__ dst, const int* __restrict__ eid,
                       const int* __restrict__ etype, int* __restrict__ cnt, int E)
{
    int e = blockIdx.x * 256 + threadIdx.x;
    if (e >= E) return;
    int seg = dst[e] * kET + etype[eid[e]];
    atomicAdd(&cnt[seg], 1);
}

__global__ void k_scan1(const int* __restrict__ cnt, int* __restrict__ excl,
                        int* __restrict__ blksum, int n)
{
    __shared__ int sm[1024];
    int i = blockIdx.x * 1024 + threadIdx.x;
    int v = (i < n) ? cnt[i] : 0;
    sm[threadIdx.x] = v;
    __syncthreads();
    for (int off = 1; off < 1024; off <<= 1) {
        int t = (threadIdx.x >= off) ? sm[threadIdx.x - off] : 0;
        __syncthreads();
        sm[threadIdx.x] += t;
        __syncthreads();
    }
    if (i < n) excl[i] = sm[threadIdx.x] - v;
    if (threadIdx.x == 1023) blksum[blockIdx.x] = sm[1023];
}

__global__ void k_scan2(int* __restrict__ blksum, int nblk)
{
    __shared__ int sm[1024];
    int v = (threadIdx.x < nblk) ? blksum[threadIdx.x] : 0;
    sm[threadIdx.x] = v;
    __syncthreads();
    for (int off = 1; off < 1024; off <<= 1) {
        int t = (threadIdx.x >= off) ? sm[threadIdx.x - off] : 0;
        __syncthreads();
        sm[threadIdx.x] += t;
        __syncthreads();
    }
    if (threadIdx.x < nblk) blksum[threadIdx.x] = sm[threadIdx.x] - v;
}

__global__ void k_scan3(int* __restrict__ excl, int* __restrict__ cursor,
                        const int* __restrict__ blksum, int n)
{
    int i = blockIdx.x * 256 + threadIdx.x;
    if (i < n) {
        int s = excl[i] + blksum[i >> 10];
        excl[i] = s;
        cursor[i] = s;
    }
}

__global__ void k_reorder(const int* __restrict__ src, const int* __restrict__ dst,
                          const int* __restrict__ eid, const int* __restrict__ etype,
                          int* __restrict__ cursor, int* __restrict__ order, int E)
{
    int e = blockIdx.x * 256 + threadIdx.x;
    if (e >= E) return;
    int seg = dst[e] * kET + etype[eid[e]];
    int p = atomicAdd(&cursor[seg], 1);
    order[p] = src[e];
}

// ---------------- per-segment gather-mean -----------------------------------
template<int C>
__global__ void k_segreduce(const int* __restrict__ starts, const int* __restrict__ cnt,
                            const int* __restrict__ order, const float* __restrict__ h,
                            float* __restrict__ mean, int nseg)
{
    constexpr int L = C / 4;          // lanes per segment (float4 each)
    constexpr int SPB = 256 / L;
    int sidx = blockIdx.x * SPB + threadIdx.x / L;
    if (sidx >= nseg) return;
    int lane = threadIdx.x % L;
    int st = starts[sidx];
    int n = cnt[sidx];
    float4 acc = {0.f, 0.f, 0.f, 0.f};
    for (int j = 0; j < n; j++) {
        int s = order[st + j];
        float4 v = reinterpret_cast<const float4*>(h + (size_t)s * C)[lane];
        acc.x += v.x; acc.y += v.y; acc.z += v.z; acc.w += v.w;
    }
    float sc = 1.0f / fmaxf((float)n, 1.0f);
    acc.x *= sc; acc.y *= sc; acc.z *= sc; acc.w *= sc;
    reinterpret_cast<float4*>(mean + (size_t)sidx * C)[lane] = acc;
}

// ---------------- fused GEMM: out = [mean | onehot(nt)*h] @ [relW; rootW] + rootb[nt]
template<int C, int RELU>
__global__ __launch_bounds__(256) void k_gemm(
    int M, int N,
    const float* __restrict__ mean,
    const float* __restrict__ h, const float* __restrict__ relW,
    const float* __restrict__ rootW, const float* __restrict__ rootb,
    const int* __restrict__ nt0, float* __restrict__ out)
{
    constexpr int K1 = kET * C;
    constexpr int K = K1 + kNT * C;
    __shared__ float aT[32][64];   // [kk][row]
    __shared__ float bT[32][64];   // [kk][col]
    const int row0 = blockIdx.x * 64;
    const int col0 = blockIdx.y * 64;
    const int tx = threadIdx.x & 15;
    const int ty = threadIdx.x >> 4;
    float acc[4][4] = {};
    const int ar = threadIdx.x >> 2;          // 0..63 row within tile
    const int akb = (threadIdx.x & 3) << 3;   // 0,8,16,24 k-offset
    const int an = row0 + ar;

    for (int k0 = 0; k0 < K; k0 += 32) {
        float av[8];
#pragma unroll
        for (int i = 0; i < 8; i++) av[i] = 0.f;
        if (an < M) {
            int kg = k0 + akb;
            if (kg < K1) {
                const float4* p = reinterpret_cast<const float4*>(mean + (size_t)an * K1 + kg);
                float4 u0 = p[0], u1 = p[1];
                av[0] = u0.x; av[1] = u0.y; av[2] = u0.z; av[3] = u0.w;
                av[4] = u1.x; av[5] = u1.y; av[6] = u1.z; av[7] = u1.w;
            } else {
                int kr = kg - K1;
                if (nt0[an] == kr / C) {
                    const float4* p = reinterpret_cast<const float4*>(h + (size_t)an * C + (kr & (C - 1)));
                    float4 u0 = p[0], u1 = p[1];
                    av[0] = u0.x; av[1] = u0.y; av[2] = u0.z; av[3] = u0.w;
                    av[4] = u1.x; av[5] = u1.y; av[6] = u1.z; av[7] = u1.w;
                }
            }
        }
#pragma unroll
        for (int i = 0; i < 8; i++) aT[akb + i][ar] = av[i];

#pragma unroll
        for (int j = 0; j < 8; j++) {
            int e = j * 256 + threadIdx.x;
            int kk = e >> 6, o = e & 63;
            int kg = k0 + kk, col = col0 + o;
            float v = 0.f;
            if (col < N) {
                if (kg < K1) v = relW[(size_t)kg * N + col];
                else         v = rootW[(size_t)(kg - K1) * N + col];
            }
            bT[kk][o] = v;
        }
        __syncthreads();
#pragma unroll
        for (int kk = 0; kk < 32; kk++) {
            float4 a = *reinterpret_cast<const float4*>(&aT[kk][ty * 4]);
            float4 b = *reinterpret_cast<const float4*>(&bT[kk][tx * 4]);
            acc[0][0] += a.x * b.x; acc[0][1] += a.x * b.y; acc[0][2] += a.x * b.z; acc[0][3] += a.x * b.w;
            acc[1][0] += a.y * b.x; acc[1][1] += a.y * b.y; acc[1][2] += a.y * b.z; acc[1][3] += a.y * b.w;
            acc[2][0] += a.z * b.x; acc[2][1] += a.z * b.y; acc[2][2] += a.z * b.z; acc[2][3] += a.z * b.w;
            acc[3][0] += a.w * b.x; acc[3][1] += a.w * b.y; acc[3][2] += a.w * b.z; acc[3][3] += a.w * b.w;
        }
        __syncthreads();
    }
#pragma unroll
    for (int i = 0; i < 4; i++) {
        int n = row0 + ty * 4 + i;
        if (n >= M) continue;
        int t = nt0[n];
#pragma unroll
        for (int j = 0; j < 4; j++) {
            int col = col0 + tx * 4 + j;
            if (col >= N) continue;
            float v = acc[i][j] + rootb[t * N + col];
            if (RELU) v = fmaxf(v, 0.f);
            out[(size_t)n * N + col] = v;
        }
    }
}

// ---------------- in-place log_softmax over rows of N cols ------------------
__global__ void k_logsm(float* __restrict__ out, int M, int N)
{
    int row = blockIdx.x * 4 + (threadIdx.x >> 6);
    if (row >= M) return;
    int lane = threadIdx.x & 63;
    float* p = out + (size_t)row * N;
    float mx = -3.4e38f;
    for (int c = lane; c < N; c += 64) mx = fmaxf(mx, p[c]);
#pragma unroll
    for (int o = 32; o > 0; o >>= 1) mx = fmaxf(mx, __shfl_xor(mx, o));
    float s = 0.f;
    for (int c = lane; c < N; c += 64) s += expf(p[c] - mx);
#pragma unroll
    for (int o = 32; o > 0; o >>= 1) s += __shfl_xor(s, o);
    float lse = mx + logf(s);
    for (int c = lane; c < N; c += 64) p[c] -= lse;
}

extern "C" void kernel_launch(void* const* d_in, const int* in_sizes, int n_in,
                              void* d_out, int out_size, void* d_ws, size_t ws_size,
                              hipStream_t stream)
{
    const int*   n_id   = (const int*)d_in[0];
    const float* x0     = (const float*)d_in[1];
    const int*   src0   = (const int*)d_in[2];
    const int*   dst0   = (const int*)d_in[3];
    const int*   eid0   = (const int*)d_in[4];
    const int*   src1   = (const int*)d_in[5];
    const int*   dst1   = (const int*)d_in[6];
    const int*   eid1   = (const int*)d_in[7];
    const int*   etype  = (const int*)d_in[8];
    const int*   ntype  = (const int*)d_in[9];
    const int*   lidx   = (const int*)d_in[10];
    const float* emb1   = (const float*)d_in[11];
    const float* emb2   = (const float*)d_in[12];
    const float* emb3   = (const float*)d_in[13];
    const float* relW0  = (const float*)d_in[14];
    const float* rootW0 = (const float*)d_in[15];
    const float* rootb0 = (const float*)d_in[16];
    const float* relW1  = (const float*)d_in[17];
    const float* rootW1 = (const float*)d_in[18];
    const float* rootb1 = (const float*)d_in[19];
    float* out = (float*)d_out;

    const int E0 = in_sizes[2];
    const int E1 = in_sizes[5];

    char* ws = (char*)d_ws;
    size_t off = 0;
    auto alloc = [&](size_t bytes) -> void* {
        void* p = ws + off;
        off = (off + bytes + 255) & ~(size_t)255;
        return p;
    };
    // buffers shared/aliased across layers (layer-1 needs are strictly smaller)
    float* h0     = (float*)alloc((size_t)kN0 * kCIN * 4);     // 61.4 MB
    int*   nt0    = (int*)alloc((size_t)kN0 * 4);
    float* mean   = (float*)alloc((size_t)kNSEG0 * kCIN * 4);  // 102.4 MB (>= NSEG1*HID)
    int*   cnt    = (int*)alloc((size_t)kNSEG0 * 4);
    int*   starts = (int*)alloc((size_t)kNSEG0 * 4);
    int*   cursor = (int*)alloc((size_t)kNSEG0 * 4);
    int*   order  = (int*)alloc((size_t)1500000 * 4);          // >= max(E0, E1)
    int*   blksum = (int*)alloc(1024 * 4);
    float* h1     = (float*)alloc((size_t)kN1 * kHID * 4);     // 41 MB

    // ---- layer 0 CSR build + gather (independent; gather can overlap) ----
    k_gather<<<(kN0 + 7) / 8, 256, 0, stream>>>(n_id, x0, emb1, emb2, emb3, ntype, lidx, h0, nt0);

    hipMemsetAsync(cnt, 0, (size_t)kNSEG0 * 4, stream);
    k_hist<<<(E0 + 255) / 256, 256, 0, stream>>>(dst0, eid0, etype, cnt, E0);
    int nblk0 = (kNSEG0 + 1023) / 1024;
    k_scan1<<<nblk0, 1024, 0, stream>>>(cnt, starts, blksum, kNSEG0);
    k_scan2<<<1, 1024, 0, stream>>>(blksum, nblk0);
    k_scan3<<<(kNSEG0 + 255) / 256, 256, 0, stream>>>(starts, cursor, blksum, kNSEG0);
    k_reorder<<<(E0 + 255) / 256, 256, 0, stream>>>(src0, dst0, eid0, etype, cursor, order, E0);
    k_segreduce<kCIN><<<(kNSEG0 + 7) / 8, 256, 0, stream>>>(starts, cnt, order, h0, mean, kNSEG0);

    dim3 g0(kN1 / 64, kHID / 64);
    k_gemm<kCIN, 1><<<g0, 256, 0, stream>>>(kN1, kHID, mean, h0, relW0, rootW0, rootb0, nt0, h1);

    // ---- layer 1 (reuse cnt/starts/cursor/order/mean) ----
    hipMemsetAsync(cnt, 0, (size_t)kNSEG1 * 4, stream);
    k_hist<<<(E1 + 255) / 256, 256, 0, stream>>>(dst1, eid1, etype, cnt, E1);
    int nblk1 = (kNSEG1 + 1023) / 1024;
    k_scan1<<<nblk1, 1024, 0, stream>>>(cnt, starts, blksum, kNSEG1);
    k_scan2<<<1, 1024, 0, stream>>>(blksum, nblk1);
    k_scan3<<<(kNSEG1 + 255) / 256, 256, 0, stream>>>(starts, cursor, blksum, kNSEG1);
    k_reorder<<<(E1 + 255) / 256, 256, 0, stream>>>(src1, dst1, eid1, etype, cursor, order, E1);
    k_segreduce<kHID><<<(kNSEG1 + 3) / 4, 256, 0, stream>>>(starts, cnt, order, h1, mean, kNSEG1);

    dim3 g1((kN2 + 63) / 64, (kOUT + 63) / 64);
    k_gemm<kHID, 0><<<g1, 256, 0, stream>>>(kN2, kOUT, mean, h1, relW1, rootW1, rootb1, nt0, out);

    k_logsm<<<(kN2 + 3) / 4, 256, 0, stream>>>(out, kN2, kOUT);
}

// Round 3
// 564.791 us; speedup vs baseline: 8.5538x; 2.0442x over previous
//
#include <hip/hip_runtime.h>
#include <hip/hip_bf16.h>
#include <cmath>

constexpr int kCIN = 128, kHID = 256, kOUT = 349;
constexpr int kNT = 4, kET = 5;
constexpr int kN0 = 120000, kN1 = 40000, kN2 = 10000;
constexpr int kNSEG0 = kN1 * kET;   // 200000
constexpr int kNSEG1 = kN2 * kET;   // 50000

typedef __bf16 bf16x8 __attribute__((ext_vector_type(8)));
typedef float f32x4 __attribute__((ext_vector_type(4)));
typedef unsigned short ushort8v __attribute__((ext_vector_type(8)));

__device__ __forceinline__ unsigned short f2b(float f) {
    unsigned int b = __float_as_uint(f);
    unsigned int r = (b + 0x7FFFu + ((b >> 16) & 1u)) >> 16;
    return (unsigned short)r;
}
__device__ __forceinline__ float b2f(unsigned short u) {
    return __uint_as_float((unsigned int)u << 16);
}

// ---------------- input gather: h0[i] = bf16(table[nt][min(li, rows-1)]) ----
__global__ void k_gather(const int* __restrict__ n_id, const float* __restrict__ x0,
                         const float* __restrict__ e1, const float* __restrict__ e2,
                         const float* __restrict__ e3, const int* __restrict__ ntype,
                         const int* __restrict__ lidx, unsigned short* __restrict__ h0b,
                         int* __restrict__ nt0)
{
    int row = blockIdx.x * 8 + (threadIdx.x >> 5);
    if (row >= kN0) return;
    int lane = threadIdx.x & 31;
    int gid = n_id[row];
    int nt = ntype[gid];
    int li = lidx[gid];
    const float* tab;
    int rows;
    if (nt == 0)      { tab = x0; rows = 100000; }
    else if (nt == 1) { tab = e1; rows = 50000; }
    else if (nt == 2) { tab = e2; rows = 50000; }
    else              { tab = e3; rows = 50000; }
    int idx = li < rows ? li : rows - 1;
    float4 v = reinterpret_cast<const float4*>(tab + (size_t)idx * kCIN)[lane];
    ushort4 o;
    o.x = f2b(v.x); o.y = f2b(v.y); o.z = f2b(v.z); o.w = f2b(v.w);
    reinterpret_cast<ushort4*>(h0b + (size_t)row * kCIN)[lane] = o;
    if (lane == 0) nt0[row] = nt;
}

// ---------------- CSR build: histogram, scan, reorder -----------------------
__global__ void k_hist(const int* __restrict__ dst, const int* __restrict__ eid,
                       const int* __restrict__ etype, int* __restrict__ cnt, int E)
{
    int e = blockIdx.x * 256 + threadIdx.x;
    if (e >= E) return;
    int seg = dst[e] * kET + etype[eid[e]];
    atomicAdd(&cnt[seg], 1);
}

__global__ void k_scan1(const int* __restrict__ cnt, int* __restrict__ excl,
                        int* __restrict__ blksum, int n)
{
    __shared__ int sm[1024];
    int i = blockIdx.x * 1024 + threadIdx.x;
    int v = (i < n) ? cnt[i] : 0;
    sm[threadIdx.x] = v;
    __syncthreads();
    for (int off = 1; off < 1024; off <<= 1) {
        int t = (threadIdx.x >= off) ? sm[threadIdx.x - off] : 0;
        __syncthreads();
        sm[threadIdx.x] += t;
        __syncthreads();
    }
    if (i < n) excl[i] = sm[threadIdx.x] - v;
    if (threadIdx.x == 1023) blksum[blockIdx.x] = sm[1023];
}

__global__ void k_scan2(int* __restrict__ blksum, int nblk)
{
    __shared__ int sm[1024];
    int v = (threadIdx.x < nblk) ? blksum[threadIdx.x] : 0;
    sm[threadIdx.x] = v;
    __syncthreads();
    for (int off = 1; off < 1024; off <<= 1) {
        int t = (threadIdx.x >= off) ? sm[threadIdx.x - off] : 0;
        __syncthreads();
        sm[threadIdx.x] += t;
        __syncthreads();
    }
    if (threadIdx.x < nblk) blksum[threadIdx.x] = sm[threadIdx.x] - v;
}

__global__ void k_scan3(int* __restrict__ excl, int* __restrict__ cursor,
                        const int* __restrict__ blksum, int n)
{
    int i = blockIdx.x * 256 + threadIdx.x;
    if (i < n) {
        int s = excl[i] + blksum[i >> 10];
        excl[i] = s;
        cursor[i] = s;
    }
}

__global__ void k_reorder(const int* __restrict__ src, const int* __restrict__ dst,
                          const int* __restrict__ eid, const int* __restrict__ etype,
                          int* __restrict__ cursor, int* __restrict__ order, int E)
{
    int e = blockIdx.x * 256 + threadIdx.x;
    if (e >= E) return;
    int seg = dst[e] * kET + etype[eid[e]];
    int p = atomicAdd(&cursor[seg], 1);
    order[p] = src[e];
}

// ---------------- per-segment gather-mean (bf16 in, bf16 out, f32 acc) ------
template<int C>
__global__ void k_segreduce(const int* __restrict__ starts, const int* __restrict__ cnt,
                            const int* __restrict__ order, const unsigned short* __restrict__ h,
                            unsigned short* __restrict__ mean, int nseg)
{
    constexpr int L = C / 4;          // lanes per segment (4 bf16 = 8B each)
    constexpr int SPB = 256 / L;
    int sidx = blockIdx.x * SPB + threadIdx.x / L;
    if (sidx >= nseg) return;
    int lane = threadIdx.x % L;
    int st = starts[sidx];
    int n = cnt[sidx];
    float a0 = 0.f, a1 = 0.f, a2 = 0.f, a3 = 0.f;
    for (int j = 0; j < n; j++) {
        int s = order[st + j];
        ushort4 v = *reinterpret_cast<const ushort4*>(h + (size_t)s * C + lane * 4);
        a0 += b2f(v.x); a1 += b2f(v.y); a2 += b2f(v.z); a3 += b2f(v.w);
    }
    float sc = 1.0f / fmaxf((float)n, 1.0f);
    ushort4 o;
    o.x = f2b(a0 * sc); o.y = f2b(a1 * sc); o.z = f2b(a2 * sc); o.w = f2b(a3 * sc);
    *reinterpret_cast<ushort4*>(mean + (size_t)sidx * C + lane * 4) = o;
}

// ---------------- weight prep: Bt[col][k] = bf16([relW;rootW][k][col]) ------
__global__ void k_prepw(const float* __restrict__ relW, const float* __restrict__ rootW,
                        unsigned short* __restrict__ Bt, int N, int Npad, int K1, int K)
{
    int i = blockIdx.x * 256 + threadIdx.x;
    if (i >= Npad * K) return;
    int col = i / K;
    int k = i - col * K;
    float v = 0.f;
    if (col < N) v = (k < K1) ? relW[(size_t)k * N + col] : rootW[(size_t)(k - K1) * N + col];
    Bt[i] = f2b(v);
}

// ---------------- MFMA GEMM: out = [mean | onehot(nt)*h] @ Bt^T + rootb[nt] -
// A (virtual, bf16): k<K1: mean[row][k];  k>=K1: (nt[row]==(k-K1)/C) ? h[row][(k-K1)%C] : 0
// Bt: [Npad][K] bf16 row-major (col-major weights).
template<int C, int RELU, int OUTBF16>
__global__ __launch_bounds__(256) void k_gemm_mfma(
    int M, int Nreal,
    const unsigned short* __restrict__ meanb,
    const unsigned short* __restrict__ hb,
    const unsigned short* __restrict__ Bt,
    const float* __restrict__ rootb,
    const int* __restrict__ nt0,
    unsigned short* __restrict__ outb, float* __restrict__ outf)
{
    constexpr int K1 = kET * C;
    constexpr int K = K1 + kNT * C;
    constexpr int LOG2C = (C == 128) ? 7 : 8;
    __shared__ __align__(16) char ldsA[128 * 128];  // 128 rows x 64 bf16 (swizzled)
    __shared__ __align__(16) char ldsB[128 * 128];  // 128 cols x 64 bf16 (swizzled)

    const int tid = threadIdx.x;
    const int row0 = blockIdx.x * 128;
    const int col0 = blockIdx.y * 128;
    const int wid = tid >> 6, lane = tid & 63;
    const int wr = (wid >> 1) * 64;     // wave row offset in tile
    const int wc = (wid & 1) * 64;      // wave col offset in tile
    const int sr = tid >> 3;            // staging row 0..31 (+p*32)
    const int skb = (tid & 7) * 16;     // staging byte offset in 128B row

    f32x4 acc[4][4] = {};

    for (int k0 = 0; k0 < K; k0 += 64) {
#pragma unroll
        for (int p = 0; p < 4; p++) {
            int r = sr + p * 32;
            int kg = k0 + (skb >> 1);
            // --- A ---
            int row = row0 + r;
            ushort8v va = {0, 0, 0, 0, 0, 0, 0, 0};
            if (row < M) {
                if (kg < K1) {
                    va = *reinterpret_cast<const ushort8v*>(meanb + (size_t)row * K1 + kg);
                } else {
                    int kr = kg - K1;
                    if (nt0[row] == (kr >> LOG2C))
                        va = *reinterpret_cast<const ushort8v*>(hb + (size_t)row * C + (kr & (C - 1)));
                }
            }
            *reinterpret_cast<ushort8v*>(&ldsA[r * 128 + (skb ^ ((r & 7) << 4))]) = va;
            // --- B ---
            int colr = col0 + r;
            ushort8v vb = *reinterpret_cast<const ushort8v*>(Bt + (size_t)colr * K + kg);
            *reinterpret_cast<ushort8v*>(&ldsB[r * 128 + (skb ^ ((r & 7) << 4))]) = vb;
        }
        __syncthreads();
#pragma unroll
        for (int kc = 0; kc < 2; kc++) {
            int kb = kc * 64 + (lane >> 4) * 16;  // byte offset of this lane's 8 bf16
            bf16x8 af[4], bfr[4];
#pragma unroll
            for (int m = 0; m < 4; m++) {
                int r = wr + m * 16 + (lane & 15);
                af[m] = *reinterpret_cast<const bf16x8*>(&ldsA[r * 128 + (kb ^ ((r & 7) << 4))]);
            }
#pragma unroll
            for (int n = 0; n < 4; n++) {
                int r = wc + n * 16 + (lane & 15);
                bfr[n] = *reinterpret_cast<const bf16x8*>(&ldsB[r * 128 + (kb ^ ((r & 7) << 4))]);
            }
#pragma unroll
            for (int m = 0; m < 4; m++)
#pragma unroll
                for (int n = 0; n < 4; n++)
                    acc[m][n] = __builtin_amdgcn_mfma_f32_16x16x32_bf16(af[m], bfr[n], acc[m][n], 0, 0, 0);
        }
        __syncthreads();
    }

    // epilogue: C/D mapping col=lane&15, row=(lane>>4)*4+j
#pragma unroll
    for (int m = 0; m < 4; m++) {
        int rbase = row0 + wr + m * 16 + (lane >> 4) * 4;
#pragma unroll
        for (int n = 0; n < 4; n++) {
            int col = col0 + wc + n * 16 + (lane & 15);
            if (col >= Nreal) continue;
            f32x4 v = acc[m][n];
#pragma unroll
            for (int j = 0; j < 4; j++) {
                int row = rbase + j;
                if (row >= M) continue;
                float x = v[j] + rootb[nt0[row] * Nreal + col];
                if (RELU) x = fmaxf(x, 0.f);
                if (OUTBF16) outb[(size_t)row * Nreal + col] = f2b(x);
                else         outf[(size_t)row * Nreal + col] = x;
            }
        }
    }
}

// ---------------- in-place log_softmax over rows of N cols ------------------
__global__ void k_logsm(float* __restrict__ out, int M, int N)
{
    int row = blockIdx.x * 4 + (threadIdx.x >> 6);
    if (row >= M) return;
    int lane = threadIdx.x & 63;
    float* p = out + (size_t)row * N;
    float mx = -3.4e38f;
    for (int c = lane; c < N; c += 64) mx = fmaxf(mx, p[c]);
#pragma unroll
    for (int o = 32; o > 0; o >>= 1) mx = fmaxf(mx, __shfl_xor(mx, o));
    float s = 0.f;
    for (int c = lane; c < N; c += 64) s += expf(p[c] - mx);
#pragma unroll
    for (int o = 32; o > 0; o >>= 1) s += __shfl_xor(s, o);
    float lse = mx + logf(s);
    for (int c = lane; c < N; c += 64) p[c] -= lse;
}

extern "C" void kernel_launch(void* const* d_in, const int* in_sizes, int n_in,
                              void* d_out, int out_size, void* d_ws, size_t ws_size,
                              hipStream_t stream)
{
    const int*   n_id   = (const int*)d_in[0];
    const float* x0     = (const float*)d_in[1];
    const int*   src0   = (const int*)d_in[2];
    const int*   dst0   = (const int*)d_in[3];
    const int*   eid0   = (const int*)d_in[4];
    const int*   src1   = (const int*)d_in[5];
    const int*   dst1   = (const int*)d_in[6];
    const int*   eid1   = (const int*)d_in[7];
    const int*   etype  = (const int*)d_in[8];
    const int*   ntype  = (const int*)d_in[9];
    const int*   lidx   = (const int*)d_in[10];
    const float* emb1   = (const float*)d_in[11];
    const float* emb2   = (const float*)d_in[12];
    const float* emb3   = (const float*)d_in[13];
    const float* relW0  = (const float*)d_in[14];
    const float* rootW0 = (const float*)d_in[15];
    const float* rootb0 = (const float*)d_in[16];
    const float* relW1  = (const float*)d_in[17];
    const float* rootW1 = (const float*)d_in[18];
    const float* rootb1 = (const float*)d_in[19];
    float* out = (float*)d_out;

    const int E0 = in_sizes[2];
    const int E1 = in_sizes[5];
    constexpr int K0 = kET * kCIN + kNT * kCIN;   // 1152
    constexpr int Kb1 = kET * kHID + kNT * kHID;  // 2304
    constexpr int Npad1 = 384;

    char* ws = (char*)d_ws;
    size_t off = 0;
    auto alloc = [&](size_t bytes) -> void* {
        void* p = ws + off;
        off = (off + bytes + 255) & ~(size_t)255;
        return p;
    };
    unsigned short* h0b   = (unsigned short*)alloc((size_t)kN0 * kCIN * 2);
    int*            nt0   = (int*)alloc((size_t)kN0 * 4);
    unsigned short* meanb = (unsigned short*)alloc((size_t)kNSEG0 * kCIN * 2); // >= NSEG1*HID
    int*            cnt    = (int*)alloc((size_t)kNSEG0 * 4);
    int*            starts = (int*)alloc((size_t)kNSEG0 * 4);
    int*            cursor = (int*)alloc((size_t)kNSEG0 * 4);
    int*            order  = (int*)alloc((size_t)1500000 * 4);
    int*            blksum = (int*)alloc(1024 * 4);
    unsigned short* h1b   = (unsigned short*)alloc((size_t)kN1 * kHID * 2);
    unsigned short* Bt0   = (unsigned short*)alloc((size_t)kHID * K0 * 2);
    unsigned short* Bt1   = (unsigned short*)alloc((size_t)Npad1 * Kb1 * 2);

    // ---- weight prep (independent) ----
    k_prepw<<<(kHID * K0 + 255) / 256, 256, 0, stream>>>(relW0, rootW0, Bt0, kHID, kHID, kET * kCIN, K0);
    k_prepw<<<(Npad1 * Kb1 + 255) / 256, 256, 0, stream>>>(relW1, rootW1, Bt1, kOUT, Npad1, kET * kHID, Kb1);

    // ---- input gather ----
    k_gather<<<(kN0 + 7) / 8, 256, 0, stream>>>(n_id, x0, emb1, emb2, emb3, ntype, lidx, h0b, nt0);

    // ---- layer 0 CSR + mean ----
    hipMemsetAsync(cnt, 0, (size_t)kNSEG0 * 4, stream);
    k_hist<<<(E0 + 255) / 256, 256, 0, stream>>>(dst0, eid0, etype, cnt, E0);
    int nblk0 = (kNSEG0 + 1023) / 1024;
    k_scan1<<<nblk0, 1024, 0, stream>>>(cnt, starts, blksum, kNSEG0);
    k_scan2<<<1, 1024, 0, stream>>>(blksum, nblk0);
    k_scan3<<<(kNSEG0 + 255) / 256, 256, 0, stream>>>(starts, cursor, blksum, kNSEG0);
    k_reorder<<<(E0 + 255) / 256, 256, 0, stream>>>(src0, dst0, eid0, etype, cursor, order, E0);
    k_segreduce<kCIN><<<(kNSEG0 + 7) / 8, 256, 0, stream>>>(starts, cnt, order, h0b, meanb, kNSEG0);

    dim3 g0((kN1 + 127) / 128, kHID / 128);
    k_gemm_mfma<kCIN, 1, 1><<<g0, 256, 0, stream>>>(kN1, kHID, meanb, h0b, Bt0, rootb0, nt0, h1b, nullptr);

    // ---- layer 1 CSR + mean ----
    hipMemsetAsync(cnt, 0, (size_t)kNSEG1 * 4, stream);
    k_hist<<<(E1 + 255) / 256, 256, 0, stream>>>(dst1, eid1, etype, cnt, E1);
    int nblk1 = (kNSEG1 + 1023) / 1024;
    k_scan1<<<nblk1, 1024, 0, stream>>>(cnt, starts, blksum, kNSEG1);
    k_scan2<<<1, 1024, 0, stream>>>(blksum, nblk1);
    k_scan3<<<(kNSEG1 + 255) / 256, 256, 0, stream>>>(starts, cursor, blksum, kNSEG1);
    k_reorder<<<(E1 + 255) / 256, 256, 0, stream>>>(src1, dst1, eid1, etype, cursor, order, E1);
    k_segreduce<kHID><<<(kNSEG1 + 3) / 4, 256, 0, stream>>>(starts, cnt, order, h1b, meanb, kNSEG1);

    dim3 g1((kN2 + 127) / 128, Npad1 / 128);
    k_gemm_mfma<kHID, 0, 0><<<g1, 256, 0, stream>>>(kN2, kOUT, meanb, h1b, Bt1, rootb1, nt0, nullptr, out);

    k_logsm<<<(kN2 + 3) / 4, 256, 0, stream>>>(out, kN2, kOUT);
}

// Round 4
// 501.784 us; speedup vs baseline: 9.6278x; 1.1256x over previous
//
#include <hip/hip_runtime.h>
#include <hip/hip_bf16.h>
#include <cmath>

constexpr int kCIN = 128, kHID = 256, kOUT = 349;
constexpr int kNT = 4, kET = 5;
constexpr int kN0 = 120000, kN1 = 40000, kN2 = 10000;
constexpr int kNSEG0 = kN1 * kET;   // 200000
constexpr int kNSEG1 = kN2 * kET;   // 50000

typedef __bf16 bf16x8 __attribute__((ext_vector_type(8)));
typedef float f32x4 __attribute__((ext_vector_type(4)));
typedef unsigned short ushort8v __attribute__((ext_vector_type(8)));

__device__ __forceinline__ unsigned short f2b(float f) {
    unsigned int b = __float_as_uint(f);
    unsigned int r = (b + 0x7FFFu + ((b >> 16) & 1u)) >> 16;
    return (unsigned short)r;
}
__device__ __forceinline__ float b2f(unsigned short u) {
    return __uint_as_float((unsigned int)u << 16);
}

// ---------------- input gather: h0[i] = bf16(table[nt][min(li, rows-1)]) ----
__global__ void k_gather(const int* __restrict__ n_id, const float* __restrict__ x0,
                         const float* __restrict__ e1, const float* __restrict__ e2,
                         const float* __restrict__ e3, const int* __restrict__ ntype,
                         const int* __restrict__ lidx, unsigned short* __restrict__ h0b,
                         int* __restrict__ nt0)
{
    int row = blockIdx.x * 8 + (threadIdx.x >> 5);
    if (row >= kN0) return;
    int lane = threadIdx.x & 31;
    int gid = n_id[row];
    int nt = ntype[gid];
    int li = lidx[gid];
    const float* tab;
    int rows;
    if (nt == 0)      { tab = x0; rows = 100000; }
    else if (nt == 1) { tab = e1; rows = 50000; }
    else if (nt == 2) { tab = e2; rows = 50000; }
    else              { tab = e3; rows = 50000; }
    int idx = li < rows ? li : rows - 1;
    float4 v = reinterpret_cast<const float4*>(tab + (size_t)idx * kCIN)[lane];
    ushort4 o;
    o.x = f2b(v.x); o.y = f2b(v.y); o.z = f2b(v.z); o.w = f2b(v.w);
    reinterpret_cast<ushort4*>(h0b + (size_t)row * kCIN)[lane] = o;
    if (lane == 0) nt0[row] = nt;
}

// ---------------- CSR build: histogram, scan, reorder -----------------------
__global__ void k_hist(const int* __restrict__ dst, const int* __restrict__ eid,
                       const int* __restrict__ etype, int* __restrict__ cnt, int E)
{
    int e = blockIdx.x * 256 + threadIdx.x;
    if (e >= E) return;
    int seg = dst[e] * kET + etype[eid[e]];
    atomicAdd(&cnt[seg], 1);
}

__global__ void k_scan1(const int* __restrict__ cnt, int* __restrict__ excl,
                        int* __restrict__ blksum, int n)
{
    __shared__ int sm[1024];
    int i = blockIdx.x * 1024 + threadIdx.x;
    int v = (i < n) ? cnt[i] : 0;
    sm[threadIdx.x] = v;
    __syncthreads();
    for (int off = 1; off < 1024; off <<= 1) {
        int t = (threadIdx.x >= off) ? sm[threadIdx.x - off] : 0;
        __syncthreads();
        sm[threadIdx.x] += t;
        __syncthreads();
    }
    if (i < n) excl[i] = sm[threadIdx.x] - v;
    if (threadIdx.x == 1023) blksum[blockIdx.x] = sm[1023];
}

__global__ void k_scan2(int* __restrict__ blksum, int nblk)
{
    __shared__ int sm[1024];
    int v = (threadIdx.x < nblk) ? blksum[threadIdx.x] : 0;
    sm[threadIdx.x] = v;
    __syncthreads();
    for (int off = 1; off < 1024; off <<= 1) {
        int t = (threadIdx.x >= off) ? sm[threadIdx.x - off] : 0;
        __syncthreads();
        sm[threadIdx.x] += t;
        __syncthreads();
    }
    if (threadIdx.x < nblk) blksum[threadIdx.x] = sm[threadIdx.x] - v;
}

__global__ void k_scan3(int* __restrict__ excl, int* __restrict__ cursor,
                        const int* __restrict__ blksum, int n)
{
    int i = blockIdx.x * 256 + threadIdx.x;
    if (i < n) {
        int s = excl[i] + blksum[i >> 10];
        excl[i] = s;
        cursor[i] = s;
    }
}

__global__ void k_reorder(const int* __restrict__ src, const int* __restrict__ dst,
                          const int* __restrict__ eid, const int* __restrict__ etype,
                          int* __restrict__ cursor, int* __restrict__ order, int E)
{
    int e = blockIdx.x * 256 + threadIdx.x;
    if (e >= E) return;
    int seg = dst[e] * kET + etype[eid[e]];
    int p = atomicAdd(&cursor[seg], 1);
    order[p] = src[e];
}

// ---------------- per-segment gather-mean (bf16 in/out, f32 acc) ------------
// 16 B (8 bf16) per lane, unroll-by-2 with independent accumulators for MLP.
template<int C>
__global__ __launch_bounds__(256) void k_segreduce(
    const int* __restrict__ starts, const int* __restrict__ cnt,
    const int* __restrict__ order, const unsigned short* __restrict__ h,
    unsigned short* __restrict__ mean, int nseg)
{
    constexpr int L = C / 8;          // lanes per segment (8 bf16 = 16B each)
    constexpr int SPB = 256 / L;
    int sidx = blockIdx.x * SPB + threadIdx.x / L;
    if (sidx >= nseg) return;
    int lane = threadIdx.x % L;
    int st = starts[sidx];
    int n = cnt[sidx];
    const unsigned short* hp = h + (size_t)lane * 8;
    float a0[8] = {0.f, 0.f, 0.f, 0.f, 0.f, 0.f, 0.f, 0.f};
    float a1[8] = {0.f, 0.f, 0.f, 0.f, 0.f, 0.f, 0.f, 0.f};
    int j = 0;
    for (; j + 2 <= n; j += 2) {
        int s0 = order[st + j];
        int s1 = order[st + j + 1];
        ushort8v v0 = *reinterpret_cast<const ushort8v*>(hp + (size_t)s0 * C);
        ushort8v v1 = *reinterpret_cast<const ushort8v*>(hp + (size_t)s1 * C);
#pragma unroll
        for (int i = 0; i < 8; i++) { a0[i] += b2f(v0[i]); a1[i] += b2f(v1[i]); }
    }
    if (j < n) {
        int s0 = order[st + j];
        ushort8v v0 = *reinterpret_cast<const ushort8v*>(hp + (size_t)s0 * C);
#pragma unroll
        for (int i = 0; i < 8; i++) a0[i] += b2f(v0[i]);
    }
    float sc = 1.0f / fmaxf((float)n, 1.0f);
    ushort8v o;
#pragma unroll
    for (int i = 0; i < 8; i++) o[i] = f2b((a0[i] + a1[i]) * sc);
    *reinterpret_cast<ushort8v*>(mean + (size_t)sidx * C + lane * 8) = o;
}

// ---------------- weight prep: Bt[col][k] = bf16([relW;rootW][k][col]) ------
__global__ void k_prepw(const float* __restrict__ relW, const float* __restrict__ rootW,
                        unsigned short* __restrict__ Bt, int N, int Npad, int K1, int K)
{
    int i = blockIdx.x * 256 + threadIdx.x;
    if (i >= Npad * K) return;
    int col = i / K;
    int k = i - col * K;
    float v = 0.f;
    if (col < N) v = (k < K1) ? relW[(size_t)k * N + col] : rootW[(size_t)(k - K1) * N + col];
    Bt[i] = f2b(v);
}

// ---------------- MFMA GEMM: out = [mean | onehot(nt)*h] @ Bt^T + rootb[nt] -
template<int C, int RELU, int OUTBF16>
__global__ __launch_bounds__(256) void k_gemm_mfma(
    int M, int Nreal,
    const unsigned short* __restrict__ meanb,
    const unsigned short* __restrict__ hb,
    const unsigned short* __restrict__ Bt,
    const float* __restrict__ rootb,
    const int* __restrict__ nt0,
    unsigned short* __restrict__ outb, float* __restrict__ outf)
{
    constexpr int K1 = kET * C;
    constexpr int K = K1 + kNT * C;
    constexpr int LOG2C = (C == 128) ? 7 : 8;
    __shared__ __align__(16) char ldsA[128 * 128];  // 128 rows x 64 bf16 (swizzled)
    __shared__ __align__(16) char ldsB[128 * 128];  // 128 cols x 64 bf16 (swizzled)

    const int tid = threadIdx.x;
    const int row0 = blockIdx.x * 128;
    const int col0 = blockIdx.y * 128;
    const int wid = tid >> 6, lane = tid & 63;
    const int wr = (wid >> 1) * 64;     // wave row offset in tile
    const int wc = (wid & 1) * 64;      // wave col offset in tile
    const int sr = tid >> 3;            // staging row 0..31 (+p*32)
    const int skb = (tid & 7) * 16;     // staging byte offset in 128B row

    f32x4 acc[4][4] = {};

    for (int k0 = 0; k0 < K; k0 += 64) {
#pragma unroll
        for (int p = 0; p < 4; p++) {
            int r = sr + p * 32;
            int kg = k0 + (skb >> 1);
            // --- A ---
            int row = row0 + r;
            ushort8v va = {0, 0, 0, 0, 0, 0, 0, 0};
            if (row < M) {
                if (kg < K1) {
                    va = *reinterpret_cast<const ushort8v*>(meanb + (size_t)row * K1 + kg);
                } else {
                    int kr = kg - K1;
                    if (nt0[row] == (kr >> LOG2C))
                        va = *reinterpret_cast<const ushort8v*>(hb + (size_t)row * C + (kr & (C - 1)));
                }
            }
            *reinterpret_cast<ushort8v*>(&ldsA[r * 128 + (skb ^ ((r & 7) << 4))]) = va;
            // --- B ---
            int colr = col0 + r;
            ushort8v vb = *reinterpret_cast<const ushort8v*>(Bt + (size_t)colr * K + kg);
            *reinterpret_cast<ushort8v*>(&ldsB[r * 128 + (skb ^ ((r & 7) << 4))]) = vb;
        }
        __syncthreads();
#pragma unroll
        for (int kc = 0; kc < 2; kc++) {
            int kb = kc * 64 + (lane >> 4) * 16;  // byte offset of this lane's 8 bf16
            bf16x8 af[4], bfr[4];
#pragma unroll
            for (int m = 0; m < 4; m++) {
                int r = wr + m * 16 + (lane & 15);
                af[m] = *reinterpret_cast<const bf16x8*>(&ldsA[r * 128 + (kb ^ ((r & 7) << 4))]);
            }
#pragma unroll
            for (int n = 0; n < 4; n++) {
                int r = wc + n * 16 + (lane & 15);
                bfr[n] = *reinterpret_cast<const bf16x8*>(&ldsB[r * 128 + (kb ^ ((r & 7) << 4))]);
            }
#pragma unroll
            for (int m = 0; m < 4; m++)
#pragma unroll
                for (int n = 0; n < 4; n++)
                    acc[m][n] = __builtin_amdgcn_mfma_f32_16x16x32_bf16(af[m], bfr[n], acc[m][n], 0, 0, 0);
        }
        __syncthreads();
    }

    // epilogue: C/D mapping col=lane&15, row=(lane>>4)*4+j
#pragma unroll
    for (int m = 0; m < 4; m++) {
        int rbase = row0 + wr + m * 16 + (lane >> 4) * 4;
#pragma unroll
        for (int n = 0; n < 4; n++) {
            int col = col0 + wc + n * 16 + (lane & 15);
            if (col >= Nreal) continue;
            f32x4 v = acc[m][n];
#pragma unroll
            for (int j = 0; j < 4; j++) {
                int row = rbase + j;
                if (row >= M) continue;
                float x = v[j] + rootb[nt0[row] * Nreal + col];
                if (RELU) x = fmaxf(x, 0.f);
                if (OUTBF16) outb[(size_t)row * Nreal + col] = f2b(x);
                else         outf[(size_t)row * Nreal + col] = x;
            }
        }
    }
}

// ---------------- in-place log_softmax over rows of N cols ------------------
__global__ void k_logsm(float* __restrict__ out, int M, int N)
{
    int row = blockIdx.x * 4 + (threadIdx.x >> 6);
    if (row >= M) return;
    int lane = threadIdx.x & 63;
    float* p = out + (size_t)row * N;
    float mx = -3.4e38f;
    for (int c = lane; c < N; c += 64) mx = fmaxf(mx, p[c]);
#pragma unroll
    for (int o = 32; o > 0; o >>= 1) mx = fmaxf(mx, __shfl_xor(mx, o));
    float s = 0.f;
    for (int c = lane; c < N; c += 64) s += expf(p[c] - mx);
#pragma unroll
    for (int o = 32; o > 0; o >>= 1) s += __shfl_xor(s, o);
    float lse = mx + logf(s);
    for (int c = lane; c < N; c += 64) p[c] -= lse;
}

extern "C" void kernel_launch(void* const* d_in, const int* in_sizes, int n_in,
                              void* d_out, int out_size, void* d_ws, size_t ws_size,
                              hipStream_t stream)
{
    const int*   n_id   = (const int*)d_in[0];
    const float* x0     = (const float*)d_in[1];
    const int*   src0   = (const int*)d_in[2];
    const int*   dst0   = (const int*)d_in[3];
    const int*   eid0   = (const int*)d_in[4];
    const int*   src1   = (const int*)d_in[5];
    const int*   dst1   = (const int*)d_in[6];
    const int*   eid1   = (const int*)d_in[7];
    const int*   etype  = (const int*)d_in[8];
    const int*   ntype  = (const int*)d_in[9];
    const int*   lidx   = (const int*)d_in[10];
    const float* emb1   = (const float*)d_in[11];
    const float* emb2   = (const float*)d_in[12];
    const float* emb3   = (const float*)d_in[13];
    const float* relW0  = (const float*)d_in[14];
    const float* rootW0 = (const float*)d_in[15];
    const float* rootb0 = (const float*)d_in[16];
    const float* relW1  = (const float*)d_in[17];
    const float* rootW1 = (const float*)d_in[18];
    const float* rootb1 = (const float*)d_in[19];
    float* out = (float*)d_out;

    const int E0 = in_sizes[2];
    const int E1 = in_sizes[5];
    constexpr int K0 = kET * kCIN + kNT * kCIN;   // 1152
    constexpr int Kb1 = kET * kHID + kNT * kHID;  // 2304
    constexpr int Npad1 = 384;

    char* ws = (char*)d_ws;
    size_t off = 0;
    auto alloc = [&](size_t bytes) -> void* {
        void* p = ws + off;
        off = (off + bytes + 255) & ~(size_t)255;
        return p;
    };
    unsigned short* h0b   = (unsigned short*)alloc((size_t)kN0 * kCIN * 2);
    int*            nt0   = (int*)alloc((size_t)kN0 * 4);
    unsigned short* meanb = (unsigned short*)alloc((size_t)kNSEG0 * kCIN * 2); // >= NSEG1*HID
    int*            cnt    = (int*)alloc((size_t)kNSEG0 * 4);
    int*            starts = (int*)alloc((size_t)kNSEG0 * 4);
    int*            cursor = (int*)alloc((size_t)kNSEG0 * 4);
    int*            order  = (int*)alloc((size_t)1500000 * 4);
    int*            blksum = (int*)alloc(1024 * 4);
    unsigned short* h1b   = (unsigned short*)alloc((size_t)kN1 * kHID * 2);
    unsigned short* Bt0   = (unsigned short*)alloc((size_t)kHID * K0 * 2);
    unsigned short* Bt1   = (unsigned short*)alloc((size_t)Npad1 * Kb1 * 2);

    // ---- weight prep (independent) ----
    k_prepw<<<(kHID * K0 + 255) / 256, 256, 0, stream>>>(relW0, rootW0, Bt0, kHID, kHID, kET * kCIN, K0);
    k_prepw<<<(Npad1 * Kb1 + 255) / 256, 256, 0, stream>>>(relW1, rootW1, Bt1, kOUT, Npad1, kET * kHID, Kb1);

    // ---- input gather ----
    k_gather<<<(kN0 + 7) / 8, 256, 0, stream>>>(n_id, x0, emb1, emb2, emb3, ntype, lidx, h0b, nt0);

    // ---- layer 0 CSR + mean ----
    hipMemsetAsync(cnt, 0, (size_t)kNSEG0 * 4, stream);
    k_hist<<<(E0 + 255) / 256, 256, 0, stream>>>(dst0, eid0, etype, cnt, E0);
    int nblk0 = (kNSEG0 + 1023) / 1024;
    k_scan1<<<nblk0, 1024, 0, stream>>>(cnt, starts, blksum, kNSEG0);
    k_scan2<<<1, 1024, 0, stream>>>(blksum, nblk0);
    k_scan3<<<(kNSEG0 + 255) / 256, 256, 0, stream>>>(starts, cursor, blksum, kNSEG0);
    k_reorder<<<(E0 + 255) / 256, 256, 0, stream>>>(src0, dst0, eid0, etype, cursor, order, E0);
    k_segreduce<kCIN><<<(kNSEG0 + 15) / 16, 256, 0, stream>>>(starts, cnt, order, h0b, meanb, kNSEG0);

    dim3 g0((kN1 + 127) / 128, kHID / 128);
    k_gemm_mfma<kCIN, 1, 1><<<g0, 256, 0, stream>>>(kN1, kHID, meanb, h0b, Bt0, rootb0, nt0, h1b, nullptr);

    // ---- layer 1 CSR + mean ----
    hipMemsetAsync(cnt, 0, (size_t)kNSEG1 * 4, stream);
    k_hist<<<(E1 + 255) / 256, 256, 0, stream>>>(dst1, eid1, etype, cnt, E1);
    int nblk1 = (kNSEG1 + 1023) / 1024;
    k_scan1<<<nblk1, 1024, 0, stream>>>(cnt, starts, blksum, kNSEG1);
    k_scan2<<<1, 1024, 0, stream>>>(blksum, nblk1);
    k_scan3<<<(kNSEG1 + 255) / 256, 256, 0, stream>>>(starts, cursor, blksum, kNSEG1);
    k_reorder<<<(E1 + 255) / 256, 256, 0, stream>>>(src1, dst1, eid1, etype, cursor, order, E1);
    k_segreduce<kHID><<<(kNSEG1 + 7) / 8, 256, 0, stream>>>(starts, cnt, order, h1b, meanb, kNSEG1);

    dim3 g1((kN2 + 127) / 128, Npad1 / 128);
    k_gemm_mfma<kHID, 0, 0><<<g1, 256, 0, stream>>>(kN2, kOUT, meanb, h1b, Bt1, rootb1, nt0, nullptr, out);

    k_logsm<<<(kN2 + 3) / 4, 256, 0, stream>>>(out, kN2, kOUT);
}

// Round 5
// 442.174 us; speedup vs baseline: 10.9258x; 1.1348x over previous
//
#include <hip/hip_runtime.h>
#include <hip/hip_bf16.h>
#include <cmath>

constexpr int kCIN = 128, kHID = 256, kOUT = 349;
constexpr int kNT = 4, kET = 5;
constexpr int kN0 = 120000, kN1 = 40000, kN2 = 10000;
constexpr int kNSEG0 = kN1 * kET;   // 200000
constexpr int kNSEG1 = kN2 * kET;   // 50000
constexpr int kNSEG = kNSEG0 + kNSEG1;  // 250000

typedef __bf16 bf16x8 __attribute__((ext_vector_type(8)));
typedef float f32x4 __attribute__((ext_vector_type(4)));
typedef unsigned short ushort8v __attribute__((ext_vector_type(8)));

__device__ __forceinline__ unsigned short f2b(float f) {
    unsigned int b = __float_as_uint(f);
    unsigned int r = (b + 0x7FFFu + ((b >> 16) & 1u)) >> 16;
    return (unsigned short)r;
}
__device__ __forceinline__ float b2f(unsigned short u) {
    return __uint_as_float((unsigned int)u << 16);
}

// ---------------- input gather: h0[i] = bf16(table[nt][min(li, rows-1)]) ----
__global__ void k_gather(const int* __restrict__ n_id, const float* __restrict__ x0,
                         const float* __restrict__ e1, const float* __restrict__ e2,
                         const float* __restrict__ e3, const int* __restrict__ ntype,
                         const int* __restrict__ lidx, unsigned short* __restrict__ h0b,
                         int* __restrict__ nt0)
{
    int row = blockIdx.x * 8 + (threadIdx.x >> 5);
    if (row >= kN0) return;
    int lane = threadIdx.x & 31;
    int gid = n_id[row];
    int nt = ntype[gid];
    int li = lidx[gid];
    const float* tab;
    int rows;
    if (nt == 0)      { tab = x0; rows = 100000; }
    else if (nt == 1) { tab = e1; rows = 50000; }
    else if (nt == 2) { tab = e2; rows = 50000; }
    else              { tab = e3; rows = 50000; }
    int idx = li < rows ? li : rows - 1;
    float4 v = reinterpret_cast<const float4*>(tab + (size_t)idx * kCIN)[lane];
    ushort4 o;
    o.x = f2b(v.x); o.y = f2b(v.y); o.z = f2b(v.z); o.w = f2b(v.w);
    reinterpret_cast<ushort4*>(h0b + (size_t)row * kCIN)[lane] = o;
    if (lane == 0) nt0[row] = nt;
}

// ---------------- combined CSR build over both layers -----------------------
__global__ void k_hist2(const int* __restrict__ dst0, const int* __restrict__ eid0, int E0,
                        const int* __restrict__ dst1, const int* __restrict__ eid1, int E1,
                        const int* __restrict__ etype, int* __restrict__ cnt)
{
    int i = blockIdx.x * 256 + threadIdx.x;
    if (i < E0) {
        atomicAdd(&cnt[dst0[i] * kET + etype[eid0[i]]], 1);
    } else if (i < E0 + E1) {
        int e = i - E0;
        atomicAdd(&cnt[kNSEG0 + dst1[e] * kET + etype[eid1[e]]], 1);
    }
}

__global__ void k_scan1(const int* __restrict__ cnt, int* __restrict__ excl,
                        int* __restrict__ blksum, int n)
{
    __shared__ int sm[1024];
    int i = blockIdx.x * 1024 + threadIdx.x;
    int v = (i < n) ? cnt[i] : 0;
    sm[threadIdx.x] = v;
    __syncthreads();
    for (int off = 1; off < 1024; off <<= 1) {
        int t = (threadIdx.x >= off) ? sm[threadIdx.x - off] : 0;
        __syncthreads();
        sm[threadIdx.x] += t;
        __syncthreads();
    }
    if (i < n) excl[i] = sm[threadIdx.x] - v;
    if (threadIdx.x == 1023) blksum[blockIdx.x] = sm[1023];
}

__global__ void k_scan2(int* __restrict__ blksum, int nblk)
{
    __shared__ int sm[1024];
    int v = (threadIdx.x < nblk) ? blksum[threadIdx.x] : 0;
    sm[threadIdx.x] = v;
    __syncthreads();
    for (int off = 1; off < 1024; off <<= 1) {
        int t = (threadIdx.x >= off) ? sm[threadIdx.x - off] : 0;
        __syncthreads();
        sm[threadIdx.x] += t;
        __syncthreads();
    }
    if (threadIdx.x < nblk) blksum[threadIdx.x] = sm[threadIdx.x] - v;
}

__global__ void k_scan3(int* __restrict__ excl, int* __restrict__ cursor,
                        const int* __restrict__ blksum, int n)
{
    int i = blockIdx.x * 256 + threadIdx.x;
    if (i < n) {
        int s = excl[i] + blksum[i >> 10];
        excl[i] = s;
        cursor[i] = s;
    }
}

__global__ void k_reorder2(const int* __restrict__ src0, const int* __restrict__ dst0,
                           const int* __restrict__ eid0, int E0,
                           const int* __restrict__ src1, const int* __restrict__ dst1,
                           const int* __restrict__ eid1, int E1,
                           const int* __restrict__ etype,
                           int* __restrict__ cursor, int* __restrict__ order)
{
    int i = blockIdx.x * 256 + threadIdx.x;
    if (i < E0) {
        int seg = dst0[i] * kET + etype[eid0[i]];
        int p = atomicAdd(&cursor[seg], 1);
        order[p] = src0[i];
    } else if (i < E0 + E1) {
        int e = i - E0;
        int seg = kNSEG0 + dst1[e] * kET + etype[eid1[e]];
        int p = atomicAdd(&cursor[seg], 1);
        order[p] = src1[e];
    }
}

// ---------------- per-segment gather-mean (bf16 in/out, f32 acc) ------------
template<int C>
__global__ __launch_bounds__(256) void k_segreduce(
    const int* __restrict__ starts, const int* __restrict__ cnt,
    const int* __restrict__ order, const unsigned short* __restrict__ h,
    unsigned short* __restrict__ mean, int nseg)
{
    constexpr int L = C / 8;          // lanes per segment (8 bf16 = 16B each)
    constexpr int SPB = 256 / L;
    int sidx = blockIdx.x * SPB + threadIdx.x / L;
    if (sidx >= nseg) return;
    int lane = threadIdx.x % L;
    int st = starts[sidx];
    int n = cnt[sidx];
    const unsigned short* hp = h + (size_t)lane * 8;
    float a0[8] = {0.f, 0.f, 0.f, 0.f, 0.f, 0.f, 0.f, 0.f};
    float a1[8] = {0.f, 0.f, 0.f, 0.f, 0.f, 0.f, 0.f, 0.f};
    int j = 0;
    for (; j + 2 <= n; j += 2) {
        int s0 = order[st + j];
        int s1 = order[st + j + 1];
        ushort8v v0 = *reinterpret_cast<const ushort8v*>(hp + (size_t)s0 * C);
        ushort8v v1 = *reinterpret_cast<const ushort8v*>(hp + (size_t)s1 * C);
#pragma unroll
        for (int i = 0; i < 8; i++) { a0[i] += b2f(v0[i]); a1[i] += b2f(v1[i]); }
    }
    if (j < n) {
        int s0 = order[st + j];
        ushort8v v0 = *reinterpret_cast<const ushort8v*>(hp + (size_t)s0 * C);
#pragma unroll
        for (int i = 0; i < 8; i++) a0[i] += b2f(v0[i]);
    }
    float sc = 1.0f / fmaxf((float)n, 1.0f);
    ushort8v o;
#pragma unroll
    for (int i = 0; i < 8; i++) o[i] = f2b((a0[i] + a1[i]) * sc);
    *reinterpret_cast<ushort8v*>(mean + (size_t)sidx * C + lane * 8) = o;
}

// ---------------- weight prep: Bt[col][k] = bf16([relW;rootW][k][col]) ------
__global__ void k_prepw(const float* __restrict__ relW, const float* __restrict__ rootW,
                        unsigned short* __restrict__ Bt, int N, int Npad, int K1, int K)
{
    int i = blockIdx.x * 256 + threadIdx.x;
    if (i >= Npad * K) return;
    int col = i / K;
    int k = i - col * K;
    float v = 0.f;
    if (col < N) v = (k < K1) ? relW[(size_t)k * N + col] : rootW[(size_t)(k - K1) * N + col];
    Bt[i] = f2b(v);
}

// ---------------- MFMA GEMM: out = [mean | onehot(nt)*h] @ Bt^T + rootb[nt] -
// Templated tile BM x BN (BM,BN in {64,128}), 4 waves as 2x2, BK=64.
template<int C, int BM, int BN, int RELU, int OUTBF16>
__global__ __launch_bounds__(256) void k_gemm_mfma(
    int M, int Nreal,
    const unsigned short* __restrict__ meanb,
    const unsigned short* __restrict__ hb,
    const unsigned short* __restrict__ Bt,
    const float* __restrict__ rootb,
    const int* __restrict__ nt0,
    unsigned short* __restrict__ outb, float* __restrict__ outf)
{
    constexpr int K1 = kET * C;
    constexpr int K = K1 + kNT * C;
    constexpr int LOG2C = (C == 128) ? 7 : 8;
    constexpr int FM = BM / 32;   // 16x16 frags per wave (M)
    constexpr int FN = BN / 32;   // 16x16 frags per wave (N)
    __shared__ __align__(16) char ldsA[BM * 128];
    __shared__ __align__(16) char ldsB[BN * 128];

    const int tid = threadIdx.x;
    const int row0 = blockIdx.x * BM;
    const int col0 = blockIdx.y * BN;
    const int wid = tid >> 6, lane = tid & 63;
    const int wrow = (wid >> 1) * (BM / 2);
    const int wcol = (wid & 1) * (BN / 2);
    const int sr = tid >> 3;            // staging row 0..31 (+p*32)
    const int skb = (tid & 7) * 16;     // staging byte offset in 128B row

    f32x4 acc[FM][FN] = {};

    for (int k0 = 0; k0 < K; k0 += 64) {
        int kg = k0 + (skb >> 1);
#pragma unroll
        for (int p = 0; p < BM / 32; p++) {
            int r = sr + p * 32;
            int row = row0 + r;
            ushort8v va = {0, 0, 0, 0, 0, 0, 0, 0};
            if (row < M) {
                if (kg < K1) {
                    va = *reinterpret_cast<const ushort8v*>(meanb + (size_t)row * K1 + kg);
                } else {
                    int kr = kg - K1;
                    if (nt0[row] == (kr >> LOG2C))
                        va = *reinterpret_cast<const ushort8v*>(hb + (size_t)row * C + (kr & (C - 1)));
                }
            }
            *reinterpret_cast<ushort8v*>(&ldsA[r * 128 + (skb ^ ((r & 7) << 4))]) = va;
        }
#pragma unroll
        for (int p = 0; p < BN / 32; p++) {
            int r = sr + p * 32;
            int colr = col0 + r;
            ushort8v vb = *reinterpret_cast<const ushort8v*>(Bt + (size_t)colr * K + kg);
            *reinterpret_cast<ushort8v*>(&ldsB[r * 128 + (skb ^ ((r & 7) << 4))]) = vb;
        }
        __syncthreads();
#pragma unroll
        for (int kc = 0; kc < 2; kc++) {
            int kb = kc * 64 + (lane >> 4) * 16;
            bf16x8 af[FM], bfr[FN];
#pragma unroll
            for (int m = 0; m < FM; m++) {
                int r = wrow + m * 16 + (lane & 15);
                af[m] = *reinterpret_cast<const bf16x8*>(&ldsA[r * 128 + (kb ^ ((r & 7) << 4))]);
            }
#pragma unroll
            for (int n = 0; n < FN; n++) {
                int r = wcol + n * 16 + (lane & 15);
                bfr[n] = *reinterpret_cast<const bf16x8*>(&ldsB[r * 128 + (kb ^ ((r & 7) << 4))]);
            }
#pragma unroll
            for (int m = 0; m < FM; m++)
#pragma unroll
                for (int n = 0; n < FN; n++)
                    acc[m][n] = __builtin_amdgcn_mfma_f32_16x16x32_bf16(af[m], bfr[n], acc[m][n], 0, 0, 0);
        }
        __syncthreads();
    }

    // epilogue: C/D mapping col=lane&15, row=(lane>>4)*4+j
#pragma unroll
    for (int m = 0; m < FM; m++) {
        int rbase = row0 + wrow + m * 16 + (lane >> 4) * 4;
#pragma unroll
        for (int n = 0; n < FN; n++) {
            int col = col0 + wcol + n * 16 + (lane & 15);
            if (col >= Nreal) continue;
            f32x4 v = acc[m][n];
#pragma unroll
            for (int j = 0; j < 4; j++) {
                int row = rbase + j;
                if (row >= M) continue;
                float x = v[j] + rootb[nt0[row] * Nreal + col];
                if (RELU) x = fmaxf(x, 0.f);
                if (OUTBF16) outb[(size_t)row * Nreal + col] = f2b(x);
                else         outf[(size_t)row * Nreal + col] = x;
            }
        }
    }
}

// ---------------- in-place log_softmax over rows of N cols ------------------
__global__ void k_logsm(float* __restrict__ out, int M, int N)
{
    int row = blockIdx.x * 4 + (threadIdx.x >> 6);
    if (row >= M) return;
    int lane = threadIdx.x & 63;
    float* p = out + (size_t)row * N;
    float mx = -3.4e38f;
    for (int c = lane; c < N; c += 64) mx = fmaxf(mx, p[c]);
#pragma unroll
    for (int o = 32; o > 0; o >>= 1) mx = fmaxf(mx, __shfl_xor(mx, o));
    float s = 0.f;
    for (int c = lane; c < N; c += 64) s += expf(p[c] - mx);
#pragma unroll
    for (int o = 32; o > 0; o >>= 1) s += __shfl_xor(s, o);
    float lse = mx + logf(s);
    for (int c = lane; c < N; c += 64) p[c] -= lse;
}

extern "C" void kernel_launch(void* const* d_in, const int* in_sizes, int n_in,
                              void* d_out, int out_size, void* d_ws, size_t ws_size,
                              hipStream_t stream)
{
    const int*   n_id   = (const int*)d_in[0];
    const float* x0     = (const float*)d_in[1];
    const int*   src0   = (const int*)d_in[2];
    const int*   dst0   = (const int*)d_in[3];
    const int*   eid0   = (const int*)d_in[4];
    const int*   src1   = (const int*)d_in[5];
    const int*   dst1   = (const int*)d_in[6];
    const int*   eid1   = (const int*)d_in[7];
    const int*   etype  = (const int*)d_in[8];
    const int*   ntype  = (const int*)d_in[9];
    const int*   lidx   = (const int*)d_in[10];
    const float* emb1   = (const float*)d_in[11];
    const float* emb2   = (const float*)d_in[12];
    const float* emb3   = (const float*)d_in[13];
    const float* relW0  = (const float*)d_in[14];
    const float* rootW0 = (const float*)d_in[15];
    const float* rootb0 = (const float*)d_in[16];
    const float* relW1  = (const float*)d_in[17];
    const float* rootW1 = (const float*)d_in[18];
    const float* rootb1 = (const float*)d_in[19];
    float* out = (float*)d_out;

    const int E0 = in_sizes[2];
    const int E1 = in_sizes[5];
    constexpr int K0 = kET * kCIN + kNT * kCIN;   // 1152
    constexpr int Kb1 = kET * kHID + kNT * kHID;  // 2304
    constexpr int Npad1 = 384;

    char* ws = (char*)d_ws;
    size_t off = 0;
    auto alloc = [&](size_t bytes) -> void* {
        void* p = ws + off;
        off = (off + bytes + 255) & ~(size_t)255;
        return p;
    };
    unsigned short* h0b   = (unsigned short*)alloc((size_t)kN0 * kCIN * 2);
    int*            nt0   = (int*)alloc((size_t)kN0 * 4);
    unsigned short* meanb = (unsigned short*)alloc((size_t)kNSEG0 * kCIN * 2); // >= NSEG1*HID
    int*            cnt    = (int*)alloc((size_t)kNSEG * 4);
    int*            starts = (int*)alloc((size_t)kNSEG * 4);
    int*            cursor = (int*)alloc((size_t)kNSEG * 4);
    int*            order  = (int*)alloc((size_t)(1500000 + 400000) * 4);
    int*            blksum = (int*)alloc(1024 * 4);
    unsigned short* h1b   = (unsigned short*)alloc((size_t)kN1 * kHID * 2);
    unsigned short* Bt0   = (unsigned short*)alloc((size_t)kHID * K0 * 2);
    unsigned short* Bt1   = (unsigned short*)alloc((size_t)Npad1 * Kb1 * 2);

    // ---- weight prep + input gather (independent of CSR build) ----
    k_prepw<<<(kHID * K0 + 255) / 256, 256, 0, stream>>>(relW0, rootW0, Bt0, kHID, kHID, kET * kCIN, K0);
    k_prepw<<<(Npad1 * Kb1 + 255) / 256, 256, 0, stream>>>(relW1, rootW1, Bt1, kOUT, Npad1, kET * kHID, Kb1);
    k_gather<<<(kN0 + 7) / 8, 256, 0, stream>>>(n_id, x0, emb1, emb2, emb3, ntype, lidx, h0b, nt0);

    // ---- combined CSR build (both layers) ----
    hipMemsetAsync(cnt, 0, (size_t)kNSEG * 4, stream);
    int Etot = E0 + E1;
    k_hist2<<<(Etot + 255) / 256, 256, 0, stream>>>(dst0, eid0, E0, dst1, eid1, E1, etype, cnt);
    int nblk = (kNSEG + 1023) / 1024;
    k_scan1<<<nblk, 1024, 0, stream>>>(cnt, starts, blksum, kNSEG);
    k_scan2<<<1, 1024, 0, stream>>>(blksum, nblk);
    k_scan3<<<(kNSEG + 255) / 256, 256, 0, stream>>>(starts, cursor, blksum, kNSEG);
    k_reorder2<<<(Etot + 255) / 256, 256, 0, stream>>>(src0, dst0, eid0, E0, src1, dst1, eid1, E1,
                                                       etype, cursor, order);

    // ---- layer 0 ----
    k_segreduce<kCIN><<<(kNSEG0 + 15) / 16, 256, 0, stream>>>(starts, cnt, order, h0b, meanb, kNSEG0);
    dim3 g0((kN1 + 63) / 64, kHID / 128);
    k_gemm_mfma<kCIN, 64, 128, 1, 1><<<g0, 256, 0, stream>>>(kN1, kHID, meanb, h0b, Bt0, rootb0, nt0, h1b, nullptr);

    // ---- layer 1 ----
    k_segreduce<kHID><<<(kNSEG1 + 7) / 8, 256, 0, stream>>>(starts + kNSEG0, cnt + kNSEG0, order, h1b, meanb, kNSEG1);
    dim3 g1((kN2 + 63) / 64, Npad1 / 64);
    k_gemm_mfma<kHID, 64, 64, 0, 0><<<g1, 256, 0, stream>>>(kN2, kOUT, meanb, h1b, Bt1, rootb1, nt0, nullptr, out);

    k_logsm<<<(kN2 + 3) / 4, 256, 0, stream>>>(out, kN2, kOUT);
}